// Round 15
// baseline (367.657 us; speedup 1.0000x reference)
//
#include <hip/hip_runtime.h>
#include <stdint.h>

#define NU 200000
#define NM 100000
#define DIM 64
#define MBK2 256         // buckets per direction
#define SP_M 391         // movie node span per bucket (ceil(NM/256))
#define SP_U 782         // user  node span per bucket (ceil(NU/256))
#define G_SC 1024        // blocks for count/pair_scatter (fixed chunk assignment)

typedef unsigned short ushort_t;
typedef __attribute__((ext_vector_type(8))) short bf16x8;
typedef __attribute__((ext_vector_type(4))) float f32x4;

// ---------------------------------------------------------------------------
// bf16 helpers (RNE)
__device__ __forceinline__ unsigned pack_bf2(float lo, float hi) {
    unsigned ul = __float_as_uint(lo); ul += 0x7fffu + ((ul >> 16) & 1u);
    unsigned uh = __float_as_uint(hi); uh += 0x7fffu + ((uh >> 16) & 1u);
    return (ul >> 16) | (uh & 0xffff0000u);
}
__device__ __forceinline__ ushort_t pack_bf1(float v) {
    unsigned u = __float_as_uint(v); u += 0x7fffu + ((u >> 16) & 1u);
    return (ushort_t)(u >> 16);
}

// v_dot2_f32_bf16: acc += pair.lo*sel.lo + pair.hi*sel.hi (1 VALU op)
__device__ __forceinline__ void dot2_acc(float& acc, unsigned pair, unsigned sel) {
    asm("v_dot2_f32_bf16 %0, %1, %2, %0" : "+v"(acc) : "v"(pair), "v"(sel));
}
__device__ __forceinline__ void acc8(float* a, const uint4& v,
                                     unsigned SEL_LO, unsigned SEL_HI) {
    dot2_acc(a[0], v.x, SEL_LO); dot2_acc(a[1], v.x, SEL_HI);
    dot2_acc(a[2], v.y, SEL_LO); dot2_acc(a[3], v.y, SEL_HI);
    dot2_acc(a[4], v.z, SEL_LO); dot2_acc(a[5], v.z, SEL_HI);
    dot2_acc(a[6], v.w, SEL_LO); dot2_acc(a[7], v.w, SEL_HI);
}

// ---------------------------------------------------------------------------
// Detect whether edge index arrays are int64 or int32.
__global__ void detect_idx_kernel(const unsigned int* __restrict__ words,
                                  int* __restrict__ flag) {
    __shared__ int nz;
    if (threadIdx.x == 0) nz = 0;
    __syncthreads();
    for (int i = threadIdx.x; i < 2048; i += blockDim.x)
        if (words[2 * i + 1] != 0u) nz = 1;
    __syncthreads();
    if (threadIdx.x == 0) *flag = (nz == 0) ? 1 : 0;   // 1 => int64
}

__device__ __forceinline__ int load_idx(const void* __restrict__ p, int e, int is64) {
    if (is64) return (int)((const long long*)p)[e];
    return ((const int*)p)[e];
}

// ---------------------------------------------------------------------------
// fp32 -> bf16 (RNE) for BOTH feature tables in one dispatch.
__global__ void conv_bf16_kernel(const float4* __restrict__ xu,
                                 const float4* __restrict__ xm,
                                 uint2* __restrict__ xu_bf,
                                 uint2* __restrict__ xm_bf) {
    const int nu4 = NU * 16, nm4 = NM * 16;
    const int stride = gridDim.x * blockDim.x;
    for (int i = blockIdx.x * blockDim.x + threadIdx.x; i < nu4 + nm4; i += stride) {
        if (i < nu4) {
            const float4 v = xu[i];
            xu_bf[i] = make_uint2(pack_bf2(v.x, v.y), pack_bf2(v.z, v.w));
        } else {
            const float4 v = xm[i - nu4];
            xm_bf[i - nu4] = make_uint2(pack_bf2(v.x, v.y), pack_bf2(v.z, v.w));
        }
    }
}

// ---------------------------------------------------------------------------
// Weight prep: 4 direction-layer tables -> wt[tbl][n][k] bf16 (k-contiguous,
// k<64 = Wl[k][n], k>=64 = Wr[k-64][n]).  4 x 8192 bf16 = 64KB.
__global__ void prep_w_kernel(const float* __restrict__ W1ml, const float* __restrict__ W1mr,
                              const float* __restrict__ W1ul, const float* __restrict__ W1ur,
                              const float* __restrict__ W2ml, const float* __restrict__ W2mr,
                              const float* __restrict__ W2ul, const float* __restrict__ W2ur,
                              ushort_t* __restrict__ wt) {
    const int t = blockIdx.x * blockDim.x + threadIdx.x;
    if (t >= 4 * 8192) return;
    const int tbl = t >> 13, r = t & 8191;
    const int n = r >> 7, k = r & 127;
    const float* Wl; const float* Wr;
    switch (tbl) {
        case 0:  Wl = W1ml; Wr = W1mr; break;
        case 1:  Wl = W1ul; Wr = W1ur; break;
        case 2:  Wl = W2ml; Wr = W2mr; break;
        default: Wl = W2ul; Wr = W2ur; break;
    }
    const float v = (k < 64) ? Wl[k * 64 + n] : Wr[(k - 64) * 64 + n];
    wt[t] = pack_bf1(v);
}

// ---------------------------------------------------------------------------
// Per-block 256-bucket histograms, both directions (bucket-major layout
// hist[b*G_SC + blk]); FIXED per-block edge chunks.
__global__ void count_kernel(const void* __restrict__ es, const void* __restrict__ ed,
                             const int* __restrict__ flag,
                             int* __restrict__ hist_m, int* __restrict__ hist_u,
                             int nE, int cpb) {
    __shared__ int h[2 * MBK2];
    for (int i = threadIdx.x; i < 2 * MBK2; i += blockDim.x) h[i] = 0;
    __syncthreads();
    const int is64 = *flag;
    const int e0 = blockIdx.x * cpb;
    const int e1 = min(nE, e0 + cpb);
    for (int e = e0 + threadIdx.x; e < e1; e += blockDim.x) {
        int s = load_idx(es, e, is64);
        int d = load_idx(ed, e, is64);
        atomicAdd(&h[(unsigned)d / SP_M], 1);
        atomicAdd(&h[MBK2 + (unsigned)s / SP_U], 1);
    }
    __syncthreads();
    for (int i = threadIdx.x; i < 2 * MBK2; i += blockDim.x) {
        if (i < MBK2) hist_m[i * G_SC + blockIdx.x] = h[i];
        else          hist_u[(i - MBK2) * G_SC + blockIdx.x] = h[i];
    }
}

// ---------------------------------------------------------------------------
// hist scan stage A: one block per (direction, bucket) row of G_SC entries.
// Exclusive-scan the row in place; write the row total to bsum[blockIdx.x].
__global__ __launch_bounds__(1024) void
hs_a_kernel(int* __restrict__ hist_m, int* __restrict__ hist_u,
            int* __restrict__ bsum) {
    const int b = blockIdx.x;            // 0..255 movie, 256..511 user
    int* hist = (b < MBK2) ? hist_m : hist_u;
    const int bucket = (b < MBK2) ? b : b - MBK2;
    const int t = threadIdx.x;           // G_SC = 1024 = blockDim
    int* row = hist + (size_t)bucket * G_SC;
    const int v = row[t];
    __shared__ int sc[1024];
    sc[t] = v;
    __syncthreads();
    for (int off = 1; off < 1024; off <<= 1) {
        int x = (t >= off) ? sc[t - off] : 0;
        __syncthreads();
        sc[t] += x;
        __syncthreads();
    }
    row[t] = sc[t] - v;                  // exclusive within row
    if (t == 1023) bsum[b] = sc[t];      // row total
}

// hist scan stage B: scan the 2x256 row totals (independent prefixes per
// direction); emit bounds[0..256] for each direction.
__global__ void hs_b_kernel(int* __restrict__ bsum,
                            int* __restrict__ bounds_m, int* __restrict__ bounds_u,
                            int nE) {
    const int t = threadIdx.x;
    if (t == 0) {
        int acc = 0;
        for (int b = 0; b < MBK2; ++b) {
            int v = bsum[b]; bsum[b] = acc; bounds_m[b] = acc; acc += v;
        }
        bounds_m[MBK2] = nE;
    } else if (t == 1) {
        int acc = 0;
        for (int b = 0; b < MBK2; ++b) {
            int v = bsum[MBK2 + b]; bsum[MBK2 + b] = acc; bounds_u[b] = acc; acc += v;
        }
        bounds_u[MBK2] = nE;
    }
}

// ---------------------------------------------------------------------------
// Level-1 scatter, deterministic (LDS cursors = hist-excl + bucket base,
// exclusive per-bucket chunks). NO global atomics.
__global__ void pair_scatter_kernel(const void* __restrict__ es,
                                    const void* __restrict__ ed,
                                    const int* __restrict__ flag,
                                    const int* __restrict__ hist_m,
                                    const int* __restrict__ hist_u,
                                    const int* __restrict__ bsum,
                                    unsigned* __restrict__ pr_m,
                                    unsigned* __restrict__ pr_u,
                                    int nE, int cpb) {
    __shared__ int cur[2 * MBK2];
    for (int i = threadIdx.x; i < 2 * MBK2; i += blockDim.x) {
        if (i < MBK2) cur[i] = hist_m[i * G_SC + blockIdx.x] + bsum[i];
        else          cur[i] = hist_u[(i - MBK2) * G_SC + blockIdx.x] + bsum[i];
    }
    __syncthreads();
    const int is64 = *flag;
    const int e0 = blockIdx.x * cpb;
    const int e1 = min(nE, e0 + cpb);
    for (int e = e0 + threadIdx.x; e < e1; e += blockDim.x) {
        const int s = load_idx(es, e, is64);
        const int d = load_idx(ed, e, is64);
        const int b0 = (unsigned)d / SP_M;
        const int b1 = (unsigned)s / SP_U;
        const int p0 = atomicAdd(&cur[b0], 1);
        pr_m[p0] = ((unsigned)(d - b0 * SP_M) << 18) | (unsigned)s;
        const int p1 = atomicAdd(&cur[MBK2 + b1], 1);
        pr_u[p1] = ((unsigned)(s - b1 * SP_U) << 17) | (unsigned)d;
    }
}

// ---------------------------------------------------------------------------
// Merged CSR build: ONE block per bucket (512 blocks = 2/CU). LDS degree
// hist -> 1-elem/thread LDS scan -> rowptr write -> adj fill into the
// bucket's XCD-exclusive contiguous region (~31KB scatter window).
__global__ __launch_bounds__(1024) void
build_csr_kernel(const unsigned* __restrict__ pr_m, const unsigned* __restrict__ pr_u,
                 const int* __restrict__ bounds_m, const int* __restrict__ bounds_u,
                 int* __restrict__ rp_m, int* __restrict__ rp_u,
                 int* __restrict__ adj_m, int* __restrict__ adj_u, int nE) {
    __shared__ int cur[SP_U];
    __shared__ int ps[1024];
    const int t = threadIdx.x;
    const int b = blockIdx.x;
    const bool mv = (b < MBK2);
    const int bb = mv ? b : b - MBK2;
    const int span  = mv ? SP_M : SP_U;
    const int shift = mv ? 18 : 17;
    const unsigned mask = (1u << shift) - 1u;
    const unsigned* pr = mv ? pr_m : pr_u;
    const int* bounds  = mv ? bounds_m : bounds_u;
    int* rp  = mv ? rp_m : rp_u;
    int* adj = mv ? adj_m : adj_u;
    const int n_tot = mv ? NM : NU;
    const int nb = bb * span;
    const int s0 = bounds[bb], s1 = bounds[bb + 1];

    if (t < span) cur[t] = 0;
    __syncthreads();
    for (int i = s0 + t; i < s1; i += 1024)
        atomicAdd(&cur[pr[i] >> shift], 1);
    __syncthreads();
    const int deg = (t < span) ? cur[t] : 0;
    ps[t] = deg;
    __syncthreads();
    for (int off = 1; off < 1024; off <<= 1) {
        int x = (t >= off) ? ps[t - off] : 0;
        __syncthreads();
        ps[t] += x;
        __syncthreads();
    }
    const int start = s0 + ps[t] - deg;
    if (t < span) {
        if (nb + t < n_tot) rp[nb + t] = start;
        cur[t] = start;
    }
    if (bb == MBK2 - 1 && t == 0) rp[n_tot] = nE;   // sentinel
    __syncthreads();
    for (int i = s0 + t; i < s1; i += 1024) {
        const unsigned w = pr[i];
        const int slot = atomicAdd(&cur[w >> shift], 1);
        adj[slot] = (int)(w & mask);
    }
}

// ---------------------------------------------------------------------------
// bf16 mean-aggregate gather, GROUP-PER-NODE layout (unchanged from r14):
// 8 nodes/wave, one node per 8-lane group; 32 rows in flight per wave.
__global__ __launch_bounds__(256) void
gather_mean_bf16_kernel(const ushort_t* __restrict__ xsrc,
                        const int* __restrict__ rowptr,
                        const int* __restrict__ adj,
                        ushort_t* __restrict__ agg,
                        int n0, int n1) {
    const unsigned SEL_LO = 0x00003f80u;   // bf16 (1.0, 0)
    const unsigned SEL_HI = 0x3f800000u;   // bf16 (0, 1.0)
    const int lane = threadIdx.x & 63;
    const int grp  = lane >> 3;            // node group 0..7
    const int col  = lane & 7;             // uint4 column (16B)
    const int wid  = (blockIdx.x * blockDim.x + threadIdx.x) >> 6;
    const int nw   = (gridDim.x * blockDim.x) >> 6;
    for (int ib = n0 + wid * 8; ib < n1; ib += nw * 8) {
        const int i = ib + grp;
        float a[8] = {0.f, 0.f, 0.f, 0.f, 0.f, 0.f, 0.f, 0.f};
        float b[8] = {0.f, 0.f, 0.f, 0.f, 0.f, 0.f, 0.f, 0.f};
        int r0 = 0, r1 = 0;
        if (i < n1) { r0 = rowptr[i]; r1 = rowptr[i + 1]; }
        int j = r0;
        for (; j + 3 < r1; j += 4) {
            const int s0 = adj[j];
            const int s1 = adj[j + 1];
            const int s2 = adj[j + 2];
            const int s3 = adj[j + 3];
            const uint4 v0 = ((const uint4*)(xsrc + (size_t)s0 * DIM))[col];
            const uint4 v1 = ((const uint4*)(xsrc + (size_t)s1 * DIM))[col];
            const uint4 v2 = ((const uint4*)(xsrc + (size_t)s2 * DIM))[col];
            const uint4 v3 = ((const uint4*)(xsrc + (size_t)s3 * DIM))[col];
            acc8(a, v0, SEL_LO, SEL_HI);
            acc8(b, v1, SEL_LO, SEL_HI);
            acc8(a, v2, SEL_LO, SEL_HI);
            acc8(b, v3, SEL_LO, SEL_HI);
        }
        for (; j < r1; ++j) {
            const int s0 = adj[j];
            const uint4 v0 = ((const uint4*)(xsrc + (size_t)s0 * DIM))[col];
            acc8(a, v0, SEL_LO, SEL_HI);
        }
#pragma unroll
        for (int k = 0; k < 8; ++k) a[k] += b[k];
        if (i < n1) {
            const float inv = 1.0f / fmaxf((float)(r1 - r0), 1.0f);
            uint4 o;
            o.x = pack_bf2(a[0] * inv, a[1] * inv);
            o.y = pack_bf2(a[2] * inv, a[3] * inv);
            o.z = pack_bf2(a[4] * inv, a[5] * inv);
            o.w = pack_bf2(a[6] * inv, a[7] * inv);
            ((uint4*)(agg + (size_t)(i - n0) * DIM))[col] = o;
        }
    }
}

// ---------------------------------------------------------------------------
// MFMA transform (unchanged): C[64][64] = [agg|xdst] @ wt + b.
template <int RELU>
__global__ __launch_bounds__(256) void
transform_mfma_kernel(const ushort_t* __restrict__ agg,
                      const ushort_t* __restrict__ xdst_b,
                      const ushort_t* __restrict__ wt,
                      const float* __restrict__ bl,
                      float* __restrict__ out_f,
                      ushort_t* __restrict__ out_b,
                      int n0, int n1) {
    __shared__ ushort_t sA[64 * 128];   // 16KB, swizzled granules
    __shared__ ushort_t sB[64 * 128];   // 16KB, swizzled granules

    const int tid = threadIdx.x;
    const int base = n0 + blockIdx.x * 64;
    {
        const uint4* w4 = (const uint4*)wt;
#pragma unroll
        for (int i = 0; i < 4; ++i) {
            const int idx = i * 256 + tid;        // 0..1023
            const int row = idx >> 4;             // n
            const int g   = idx & 15;             // granule (8 bf16)
            ((uint4*)sB)[row * 16 + (g ^ (row & 15))] = w4[idx];
        }
    }
#pragma unroll
    for (int i = 0; i < 4; ++i) {
        const int idx = i * 256 + tid;
        const int ln   = idx >> 4;                // node local 0..63
        const int g    = idx & 15;                // granule: 0-7 agg, 8-15 xdst
        const int node = base + ln;
        uint4 v = make_uint4(0, 0, 0, 0);
        if (node < n1)
            v = (g < 8) ? ((const uint4*)(agg + (size_t)(node - n0) * DIM))[g]
                        : ((const uint4*)(xdst_b + (size_t)node * DIM))[g - 8];
        ((uint4*)sA)[ln * 16 + (g ^ (ln & 15))] = v;
    }
    __syncthreads();

    const int w    = tid >> 6;       // wave 0..3 -> node rows w*16..+15
    const int lane = tid & 63;
    const int m    = lane & 15;
    const int kg   = lane >> 4;      // k-group (8 bf16 each)
    f32x4 acc0 = {0.f, 0.f, 0.f, 0.f}, acc1 = acc0, acc2 = acc0, acc3 = acc0;
    const int ar = w * 16 + m;       // A row
#pragma unroll
    for (int kk = 0; kk < 4; ++kk) {
        const int g = kk * 4 + kg;   // granule index of this fragment's 8 k
        const bf16x8 afr = ((const bf16x8*)sA)[ar * 16 + (g ^ (ar & 15))];
        {
            const int br = m;
            const bf16x8 bfr = ((const bf16x8*)sB)[br * 16 + (g ^ (br & 15))];
            acc0 = __builtin_amdgcn_mfma_f32_16x16x32_bf16(afr, bfr, acc0, 0, 0, 0);
        }
        {
            const int br = 16 + m;
            const bf16x8 bfr = ((const bf16x8*)sB)[br * 16 + (g ^ (br & 15))];
            acc1 = __builtin_amdgcn_mfma_f32_16x16x32_bf16(afr, bfr, acc1, 0, 0, 0);
        }
        {
            const int br = 32 + m;
            const bf16x8 bfr = ((const bf16x8*)sB)[br * 16 + (g ^ (br & 15))];
            acc2 = __builtin_amdgcn_mfma_f32_16x16x32_bf16(afr, bfr, acc2, 0, 0, 0);
        }
        {
            const int br = 48 + m;
            const bf16x8 bfr = ((const bf16x8*)sB)[br * 16 + (g ^ (br & 15))];
            acc3 = __builtin_amdgcn_mfma_f32_16x16x32_bf16(afr, bfr, acc3, 0, 0, 0);
        }
    }
    const int col = lane & 15;
    const int rb  = (lane >> 4) * 4;
    f32x4 av[4] = {acc0, acc1, acc2, acc3};
#pragma unroll
    for (int ni = 0; ni < 4; ++ni) {
        const int n = ni * 16 + col;
        const float bias = bl[n];
#pragma unroll
        for (int r = 0; r < 4; ++r) {
            const int node = base + w * 16 + rb + r;
            if (node < n1) {
                float v = av[ni][r] + bias;
                if (RELU) v = fmaxf(v, 0.f);
                if (out_f) out_f[(size_t)node * DIM + n] = v;
                if (out_b) out_b[(size_t)node * DIM + n] = pack_bf1(v);
            }
        }
    }
}

// ---------------------------------------------------------------------------
extern "C" void kernel_launch(void* const* d_in, const int* in_sizes, int n_in,
                              void* d_out, int out_size, void* d_ws, size_t ws_size,
                              hipStream_t stream) {
    const float* x_user  = (const float*)d_in[0];
    const float* x_movie = (const float*)d_in[1];
    const void*  e_src   = d_in[2];
    const void*  e_dst   = d_in[3];
    const float* W1_um_l = (const float*)d_in[4];
    const float* W1_um_r = (const float*)d_in[5];
    const float* W1_mu_l = (const float*)d_in[6];
    const float* W1_mu_r = (const float*)d_in[7];
    const float* W2_um_l = (const float*)d_in[8];
    const float* W2_um_r = (const float*)d_in[9];
    const float* W2_mu_l = (const float*)d_in[10];
    const float* W2_mu_r = (const float*)d_in[11];
    const float* b1_um = (const float*)d_in[12];
    const float* b1_mu = (const float*)d_in[13];
    const float* b2_um = (const float*)d_in[14];
    const float* b2_mu = (const float*)d_in[15];
    const int nE = in_sizes[2];
    const int cpb = (nE + G_SC - 1) / G_SC;

    auto al = [](size_t b) { return (b + 255) & ~(size_t)255; };
    const size_t fixed_b = al(4) + al(((size_t)NU + 1) * 4) + al(((size_t)NM + 1) * 4)
                         + 2 * al((size_t)MBK2 * G_SC * 4) + 2 * al((MBK2 + 1) * 4)
                         + al(2 * MBK2 * 4)
                         + 2 * al((size_t)nE * 4) + al(4 * 8192 * 2);
    const size_t a1_b = al((size_t)NU * DIM * 2);
    const size_t a2_b = al((size_t)NM * DIM * 2);
    const size_t pair_b = (size_t)2 * nE * 4;
    int CHKr = 50000;
    {
        const int cand[3] = {200000, 100000, 50000};
        for (int k = 0; k < 3; ++k) {
            size_t bphase = (size_t)cand[k] * DIM * 2 + (size_t)NM * DIM * 2 + 1024;
            size_t need = fixed_b + a1_b + a2_b +
                          al(bphase > pair_b ? bphase : pair_b) + 4096;
            if (need <= ws_size) { CHKr = cand[k]; break; }
        }
    }

    char* ws = (char*)d_ws;
    size_t off = 0;
    auto carve = [&](size_t bytes) {
        void* p = ws + off;
        off += al(bytes);
        return p;
    };
    int*      flag     = (int*)carve(4);
    int*      rp_u     = (int*)carve(((size_t)NU + 1) * 4);
    int*      rp_m     = (int*)carve(((size_t)NM + 1) * 4);
    int*      hist_m   = (int*)carve((size_t)MBK2 * G_SC * 4);
    int*      hist_u   = (int*)carve((size_t)MBK2 * G_SC * 4);
    int*      bounds_m = (int*)carve((MBK2 + 1) * 4);
    int*      bounds_u = (int*)carve((MBK2 + 1) * 4);
    int*      bsum     = (int*)carve(2 * MBK2 * 4);
    int*      adj_u    = (int*)carve((size_t)nE * 4);
    int*      adj_m    = (int*)carve((size_t)nE * 4);
    ushort_t* wt_all   = (ushort_t*)carve(4 * 8192 * 2);    // 4 x [64][128] bf16
    ushort_t* A1 = (ushort_t*)carve((size_t)NU * DIM * 2);  // xu_bf then u1_bf
    ushort_t* A2 = (ushort_t*)carve((size_t)NM * DIM * 2);  // m1_bf
    size_t bphase = (size_t)CHKr * DIM * 2 + (size_t)NM * DIM * 2 + 1024;
    char*     B      = (char*)carve(bphase > pair_b ? bphase : pair_b);
    unsigned* pr_m   = (unsigned*)B;                        // phase A
    unsigned* pr_u   = (unsigned*)(B + (size_t)nE * 4);     // phase A
    ushort_t* agg_bf = (ushort_t*)B;                        // phase B
    ushort_t* xm_bf  = (ushort_t*)(B + al((size_t)CHKr * DIM * 2)); // phase B
    ushort_t* xu_bf  = A1;
    ushort_t* u1_bf  = A1;
    ushort_t* m1_bf  = A2;
    ushort_t* wt1m = wt_all;            // layer1 movie (W1_um)
    ushort_t* wt1u = wt_all + 8192;     // layer1 user  (W1_mu)
    ushort_t* wt2m = wt_all + 16384;    // layer2 movie (W2_um)
    ushort_t* wt2u = wt_all + 24576;    // layer2 user  (W2_mu)

    float* u2 = (float*)d_out;                    // [NU,64]
    float* m2 = (float*)d_out + (size_t)NU * DIM; // [NM,64]

    // ---- build CSR (both directions): fine radix binning, zero global
    //      atomics; 512 fill blocks (2/CU) ----
    detect_idx_kernel<<<1, 256, 0, stream>>>((const unsigned int*)e_src, flag);
    count_kernel<<<G_SC, 256, 0, stream>>>(e_src, e_dst, flag,
                                           hist_m, hist_u, nE, cpb);
    hs_a_kernel<<<2 * MBK2, 1024, 0, stream>>>(hist_m, hist_u, bsum);
    hs_b_kernel<<<1, 64, 0, stream>>>(bsum, bounds_m, bounds_u, nE);
    pair_scatter_kernel<<<G_SC, 256, 0, stream>>>(e_src, e_dst, flag,
                                                  hist_m, hist_u, bsum,
                                                  pr_m, pr_u, nE, cpb);
    build_csr_kernel<<<2 * MBK2, 1024, 0, stream>>>(pr_m, pr_u,
                                                    bounds_m, bounds_u,
                                                    rp_m, rp_u, adj_m, adj_u, nE);
    // pr_m/pr_u dead from here; B switches to agg_bf/xm_bf.

    // ---- bf16 sources + transposed bf16 weights ----
    conv_bf16_kernel<<<2048, 256, 0, stream>>>((const float4*)x_user,
                                               (const float4*)x_movie,
                                               (uint2*)xu_bf, (uint2*)xm_bf);
    prep_w_kernel<<<128, 256, 0, stream>>>(W1_um_l, W1_um_r, W1_mu_l, W1_mu_r,
                                           W2_um_l, W2_um_r, W2_mu_l, W2_mu_r,
                                           wt_all);

    auto run_dir = [&](const ushort_t* src_bf, const int* rp, const int* adj,
                       const ushort_t* xdst_bf, const ushort_t* wt,
                       const float* bl, float* outf, ushort_t* outb,
                       int n_tot, int relu) {
        for (int n0 = 0; n0 < n_tot; n0 += CHKr) {
            const int n1 = min(n_tot, n0 + CHKr);
            const int gb = (n1 - n0 + 31) / 32;     // 8 nodes/wave, 4 waves/blk
            const int tb = (n1 - n0 + 63) / 64;
            gather_mean_bf16_kernel<<<gb, 256, 0, stream>>>(src_bf, rp, adj,
                                                            agg_bf, n0, n1);
            if (relu)
                transform_mfma_kernel<1><<<tb, 256, 0, stream>>>(agg_bf, xdst_bf,
                    wt, bl, outf, outb, n0, n1);
            else
                transform_mfma_kernel<0><<<tb, 256, 0, stream>>>(agg_bf, xdst_bf,
                    wt, bl, outf, outb, n0, n1);
        }
    };

    // ---- layer 1 (bf16 intermediates only) ----
    run_dir(xu_bf, rp_m, adj_m, xm_bf, wt1m, b1_um, nullptr, m1_bf, NM, 1);
    run_dir(xm_bf, rp_u, adj_u, xu_bf, wt1u, b1_mu, nullptr, u1_bf, NU, 1);
    // ---- layer 2 (fp32 outputs straight to d_out) ----
    run_dir(u1_bf, rp_m, adj_m, m1_bf, wt2m, b2_um, m2, nullptr, NM, 0);
    run_dir(m1_bf, rp_u, adj_u, u1_bf, wt2u, b2_mu, u2, nullptr, NU, 0);
}

// Round 16
// 348.613 us; speedup vs baseline: 1.0546x; 1.0546x over previous
//
#include <hip/hip_runtime.h>
#include <stdint.h>

#define NU 200000
#define NM 100000
#define DIM 64
#define MBK2 64          // buckets per direction
#define SP_M 1563        // movie node span per bucket (ceil(NM/64))
#define SP_U 3125        // user  node span per bucket (NU/64)
#define G_SC 1024        // blocks for count/pair_scatter (fixed chunk assignment)

typedef unsigned short ushort_t;
typedef __attribute__((ext_vector_type(8))) short bf16x8;
typedef __attribute__((ext_vector_type(4))) float f32x4;

// ---------------------------------------------------------------------------
// bf16 helpers (RNE)
__device__ __forceinline__ unsigned pack_bf2(float lo, float hi) {
    unsigned ul = __float_as_uint(lo); ul += 0x7fffu + ((ul >> 16) & 1u);
    unsigned uh = __float_as_uint(hi); uh += 0x7fffu + ((uh >> 16) & 1u);
    return (ul >> 16) | (uh & 0xffff0000u);
}
__device__ __forceinline__ ushort_t pack_bf1(float v) {
    unsigned u = __float_as_uint(v); u += 0x7fffu + ((u >> 16) & 1u);
    return (ushort_t)(u >> 16);
}

// v_dot2_f32_bf16: acc += pair.lo*sel.lo + pair.hi*sel.hi (1 VALU op)
__device__ __forceinline__ void dot2_acc(float& acc, unsigned pair, unsigned sel) {
    asm("v_dot2_f32_bf16 %0, %1, %2, %0" : "+v"(acc) : "v"(pair), "v"(sel));
}
__device__ __forceinline__ void acc8(float* a, const uint4& v,
                                     unsigned SEL_LO, unsigned SEL_HI) {
    dot2_acc(a[0], v.x, SEL_LO); dot2_acc(a[1], v.x, SEL_HI);
    dot2_acc(a[2], v.y, SEL_LO); dot2_acc(a[3], v.y, SEL_HI);
    dot2_acc(a[4], v.z, SEL_LO); dot2_acc(a[5], v.z, SEL_HI);
    dot2_acc(a[6], v.w, SEL_LO); dot2_acc(a[7], v.w, SEL_HI);
}

// ---------------------------------------------------------------------------
// Detect whether edge index arrays are int64 or int32.
__global__ void detect_idx_kernel(const unsigned int* __restrict__ words,
                                  int* __restrict__ flag) {
    __shared__ int nz;
    if (threadIdx.x == 0) nz = 0;
    __syncthreads();
    for (int i = threadIdx.x; i < 2048; i += blockDim.x)
        if (words[2 * i + 1] != 0u) nz = 1;
    __syncthreads();
    if (threadIdx.x == 0) *flag = (nz == 0) ? 1 : 0;   // 1 => int64
}

__device__ __forceinline__ int load_idx(const void* __restrict__ p, int e, int is64) {
    if (is64) return (int)((const long long*)p)[e];
    return ((const int*)p)[e];
}

// ---------------------------------------------------------------------------
// Fused prep: fp32->bf16 (RNE) for BOTH feature tables + transposed bf16
// weight tables (4 x [64 n][128 k], k<64 = Wl[k][n], k>=64 = Wr[k-64][n]).
__global__ void conv_prep_kernel(const float4* __restrict__ xu,
                                 const float4* __restrict__ xm,
                                 uint2* __restrict__ xu_bf,
                                 uint2* __restrict__ xm_bf,
                                 const float* __restrict__ W1ml, const float* __restrict__ W1mr,
                                 const float* __restrict__ W1ul, const float* __restrict__ W1ur,
                                 const float* __restrict__ W2ml, const float* __restrict__ W2mr,
                                 const float* __restrict__ W2ul, const float* __restrict__ W2ur,
                                 ushort_t* __restrict__ wt) {
    const int nu4 = NU * 16, nm4 = NM * 16;
    const int stride = gridDim.x * blockDim.x;
    const int gid = blockIdx.x * blockDim.x + threadIdx.x;
    for (int i = gid; i < nu4 + nm4; i += stride) {
        if (i < nu4) {
            const float4 v = xu[i];
            xu_bf[i] = make_uint2(pack_bf2(v.x, v.y), pack_bf2(v.z, v.w));
        } else {
            const float4 v = xm[i - nu4];
            xm_bf[i - nu4] = make_uint2(pack_bf2(v.x, v.y), pack_bf2(v.z, v.w));
        }
    }
    if (gid < 4 * 8192) {
        const int tbl = gid >> 13, r = gid & 8191;
        const int n = r >> 7, k = r & 127;
        const float* Wl; const float* Wr;
        switch (tbl) {
            case 0:  Wl = W1ml; Wr = W1mr; break;
            case 1:  Wl = W1ul; Wr = W1ur; break;
            case 2:  Wl = W2ml; Wr = W2mr; break;
            default: Wl = W2ul; Wr = W2ur; break;
        }
        const float v = (k < 64) ? Wl[k * 64 + n] : Wr[(k - 64) * 64 + n];
        wt[gid] = pack_bf1(v);
    }
}

// ---------------------------------------------------------------------------
// Per-block 64-bucket histograms, both directions (bucket-major layout
// hist[b*G_SC + blk]); FIXED per-block edge chunks.
__global__ void count_kernel(const void* __restrict__ es, const void* __restrict__ ed,
                             const int* __restrict__ flag,
                             int* __restrict__ hist_m, int* __restrict__ hist_u,
                             int nE, int cpb) {
    __shared__ int h[2 * MBK2];
    if (threadIdx.x < 2 * MBK2) h[threadIdx.x] = 0;
    __syncthreads();
    const int is64 = *flag;
    const int e0 = blockIdx.x * cpb;
    const int e1 = min(nE, e0 + cpb);
    for (int e = e0 + threadIdx.x; e < e1; e += blockDim.x) {
        int s = load_idx(es, e, is64);
        int d = load_idx(ed, e, is64);
        atomicAdd(&h[(unsigned)d / SP_M], 1);
        atomicAdd(&h[MBK2 + (unsigned)s / SP_U], 1);
    }
    __syncthreads();
    if (threadIdx.x < MBK2)
        hist_m[threadIdx.x * G_SC + blockIdx.x] = h[threadIdx.x];
    else if (threadIdx.x < 2 * MBK2)
        hist_u[(threadIdx.x - MBK2) * G_SC + blockIdx.x] = h[threadIdx.x];
}

// ---------------------------------------------------------------------------
// Exclusive scan of per-block bucket histogram (64*G_SC, bucket-major) in
// place; emits bounds[0..64]. 2 blocks (movie, user).
__global__ __launch_bounds__(1024) void
hist_scan_kernel(int* __restrict__ hist_m, int* __restrict__ hist_u,
                 int* __restrict__ bounds_m, int* __restrict__ bounds_u, int nE) {
    int* hist   = (blockIdx.x == 0) ? hist_m : hist_u;
    int* bounds = (blockIdx.x == 0) ? bounds_m : bounds_u;
    const int t = threadIdx.x;          // 1024 threads x 64 = 64*G_SC
    const int base = t * 64;
    int v[64];
    int tot = 0;
#pragma unroll
    for (int k = 0; k < 64; ++k) { v[k] = hist[base + k]; tot += v[k]; }
    __shared__ int sc[1024];
    sc[t] = tot;
    __syncthreads();
    for (int off = 1; off < 1024; off <<= 1) {
        int x = (t >= off) ? sc[t - off] : 0;
        __syncthreads();
        sc[t] += x;
        __syncthreads();
    }
    int excl = sc[t] - tot;
#pragma unroll
    for (int k = 0; k < 64; ++k) { int tmp = v[k]; hist[base + k] = excl; excl += tmp; }
    __syncthreads();
    if (t < MBK2) bounds[t] = hist[t * G_SC];
    else if (t == MBK2) bounds[MBK2] = nE;
}

// ---------------------------------------------------------------------------
// Level-1 scatter, deterministic (LDS cursors, exclusive per-bucket chunks).
__global__ void pair_scatter_kernel(const void* __restrict__ es,
                                    const void* __restrict__ ed,
                                    const int* __restrict__ flag,
                                    const int* __restrict__ hist_m,
                                    const int* __restrict__ hist_u,
                                    unsigned* __restrict__ pr_m,
                                    unsigned* __restrict__ pr_u,
                                    int nE, int cpb) {
    __shared__ int cur[2 * MBK2];
    if (threadIdx.x < MBK2)
        cur[threadIdx.x] = hist_m[threadIdx.x * G_SC + blockIdx.x];
    else if (threadIdx.x < 2 * MBK2)
        cur[threadIdx.x] = hist_u[(threadIdx.x - MBK2) * G_SC + blockIdx.x];
    __syncthreads();
    const int is64 = *flag;
    const int e0 = blockIdx.x * cpb;
    const int e1 = min(nE, e0 + cpb);
    for (int e = e0 + threadIdx.x; e < e1; e += blockDim.x) {
        const int s = load_idx(es, e, is64);
        const int d = load_idx(ed, e, is64);
        const int b0 = (unsigned)d / SP_M;
        const int b1 = (unsigned)s / SP_U;
        const int p0 = atomicAdd(&cur[b0], 1);
        pr_m[p0] = ((unsigned)(d - b0 * SP_M) << 18) | (unsigned)s;
        const int p1 = atomicAdd(&cur[MBK2 + b1], 1);
        pr_u[p1] = ((unsigned)(s - b1 * SP_U) << 17) | (unsigned)d;
    }
}

// ---------------------------------------------------------------------------
// Merged CSR build: ONE block per bucket (LDS degree hist -> LDS scan ->
// rowptr write -> adj fill into XCD-exclusive region).
__global__ __launch_bounds__(1024) void
build_csr_kernel(const unsigned* __restrict__ pr_m, const unsigned* __restrict__ pr_u,
                 const int* __restrict__ bounds_m, const int* __restrict__ bounds_u,
                 int* __restrict__ rp_m, int* __restrict__ rp_u,
                 int* __restrict__ adj_m, int* __restrict__ adj_u, int nE) {
    __shared__ int cur[SP_U];
    __shared__ int ps[1024];
    const int t = threadIdx.x;
    const int b = blockIdx.x;
    const bool mv = (b < MBK2);
    const int bb = mv ? b : b - MBK2;
    const int span  = mv ? SP_M : SP_U;
    const int shift = mv ? 18 : 17;
    const unsigned mask = (1u << shift) - 1u;
    const unsigned* pr = mv ? pr_m : pr_u;
    const int* bounds  = mv ? bounds_m : bounds_u;
    int* rp  = mv ? rp_m : rp_u;
    int* adj = mv ? adj_m : adj_u;
    const int n_tot = mv ? NM : NU;
    const int nb = bb * span;
    const int s0 = bounds[bb], s1 = bounds[bb + 1];

    for (int i = t; i < span; i += 1024) cur[i] = 0;
    __syncthreads();
    for (int i = s0 + t; i < s1; i += 1024)
        atomicAdd(&cur[pr[i] >> shift], 1);
    __syncthreads();
    int v[4];
    int loc = 0;
#pragma unroll
    for (int k = 0; k < 4; ++k) {
        const int i = t * 4 + k;
        v[k] = (i < span) ? cur[i] : 0;
        loc += v[k];
    }
    ps[t] = loc;
    __syncthreads();
    for (int off = 1; off < 1024; off <<= 1) {
        int x = (t >= off) ? ps[t - off] : 0;
        __syncthreads();
        ps[t] += x;
        __syncthreads();
    }
    int run = s0 + ps[t] - loc;
#pragma unroll
    for (int k = 0; k < 4; ++k) {
        const int i = t * 4 + k;
        if (i < span) {
            if (nb + i < n_tot) rp[nb + i] = run;
            cur[i] = run;
            run += v[k];
        }
    }
    if (bb == MBK2 - 1 && t == 0) rp[n_tot] = nE;   // sentinel
    __syncthreads();
    for (int i = s0 + t; i < s1; i += 1024) {
        const unsigned w = pr[i];
        const int slot = atomicAdd(&cur[w >> shift], 1);
        adj[slot] = (int)(w & mask);
    }
}

// ---------------------------------------------------------------------------
// bf16 mean-aggregate gather, GROUP-PER-NODE layout: 8 nodes per wave, one
// node per 8-lane group (col = lane&7 owns dims 8c..8c+7). Each group walks
// its adjacency with a 4-deep unroll -> 32 distinct rows in flight per wave.
// No cross-lane reduction. Writes: 8 consecutive rows = 1KB coalesced.
__global__ __launch_bounds__(256) void
gather_mean_bf16_kernel(const ushort_t* __restrict__ xsrc,
                        const int* __restrict__ rowptr,
                        const int* __restrict__ adj,
                        ushort_t* __restrict__ agg,
                        int n0, int n1) {
    const unsigned SEL_LO = 0x00003f80u;   // bf16 (1.0, 0)
    const unsigned SEL_HI = 0x3f800000u;   // bf16 (0, 1.0)
    const int lane = threadIdx.x & 63;
    const int grp  = lane >> 3;            // node group 0..7
    const int col  = lane & 7;             // uint4 column (16B)
    const int wid  = (blockIdx.x * blockDim.x + threadIdx.x) >> 6;
    const int nw   = (gridDim.x * blockDim.x) >> 6;
    for (int ib = n0 + wid * 8; ib < n1; ib += nw * 8) {
        const int i = ib + grp;
        float a[8] = {0.f, 0.f, 0.f, 0.f, 0.f, 0.f, 0.f, 0.f};
        float b[8] = {0.f, 0.f, 0.f, 0.f, 0.f, 0.f, 0.f, 0.f};
        int r0 = 0, r1 = 0;
        if (i < n1) { r0 = rowptr[i]; r1 = rowptr[i + 1]; }
        int j = r0;
        for (; j + 3 < r1; j += 4) {
            const int s0 = adj[j];
            const int s1 = adj[j + 1];
            const int s2 = adj[j + 2];
            const int s3 = adj[j + 3];
            const uint4 v0 = ((const uint4*)(xsrc + (size_t)s0 * DIM))[col];
            const uint4 v1 = ((const uint4*)(xsrc + (size_t)s1 * DIM))[col];
            const uint4 v2 = ((const uint4*)(xsrc + (size_t)s2 * DIM))[col];
            const uint4 v3 = ((const uint4*)(xsrc + (size_t)s3 * DIM))[col];
            acc8(a, v0, SEL_LO, SEL_HI);
            acc8(b, v1, SEL_LO, SEL_HI);
            acc8(a, v2, SEL_LO, SEL_HI);
            acc8(b, v3, SEL_LO, SEL_HI);
        }
        for (; j < r1; ++j) {
            const int s0 = adj[j];
            const uint4 v0 = ((const uint4*)(xsrc + (size_t)s0 * DIM))[col];
            acc8(a, v0, SEL_LO, SEL_HI);
        }
#pragma unroll
        for (int k = 0; k < 8; ++k) a[k] += b[k];
        if (i < n1) {
            const float inv = 1.0f / fmaxf((float)(r1 - r0), 1.0f);
            uint4 o;
            o.x = pack_bf2(a[0] * inv, a[1] * inv);
            o.y = pack_bf2(a[2] * inv, a[3] * inv);
            o.z = pack_bf2(a[4] * inv, a[5] * inv);
            o.w = pack_bf2(a[6] * inv, a[7] * inv);
            ((uint4*)(agg + (size_t)(i - n0) * DIM))[col] = o;
        }
    }
}

// ---------------------------------------------------------------------------
// MFMA transform: C[64][64] = [agg|xdst] @ wt + b.
template <int RELU>
__global__ __launch_bounds__(256) void
transform_mfma_kernel(const ushort_t* __restrict__ agg,
                      const ushort_t* __restrict__ xdst_b,
                      const ushort_t* __restrict__ wt,
                      const float* __restrict__ bl,
                      float* __restrict__ out_f,
                      ushort_t* __restrict__ out_b,
                      int n0, int n1) {
    __shared__ ushort_t sA[64 * 128];   // 16KB, swizzled granules
    __shared__ ushort_t sB[64 * 128];   // 16KB, swizzled granules

    const int tid = threadIdx.x;
    const int base = n0 + blockIdx.x * 64;
    {
        const uint4* w4 = (const uint4*)wt;
#pragma unroll
        for (int i = 0; i < 4; ++i) {
            const int idx = i * 256 + tid;        // 0..1023
            const int row = idx >> 4;             // n
            const int g   = idx & 15;             // granule (8 bf16)
            ((uint4*)sB)[row * 16 + (g ^ (row & 15))] = w4[idx];
        }
    }
#pragma unroll
    for (int i = 0; i < 4; ++i) {
        const int idx = i * 256 + tid;
        const int ln   = idx >> 4;                // node local 0..63
        const int g    = idx & 15;                // granule: 0-7 agg, 8-15 xdst
        const int node = base + ln;
        uint4 v = make_uint4(0, 0, 0, 0);
        if (node < n1)
            v = (g < 8) ? ((const uint4*)(agg + (size_t)(node - n0) * DIM))[g]
                        : ((const uint4*)(xdst_b + (size_t)node * DIM))[g - 8];
        ((uint4*)sA)[ln * 16 + (g ^ (ln & 15))] = v;
    }
    __syncthreads();

    const int w    = tid >> 6;       // wave 0..3 -> node rows w*16..+15
    const int lane = tid & 63;
    const int m    = lane & 15;
    const int kg   = lane >> 4;      // k-group (8 bf16 each)
    f32x4 acc0 = {0.f, 0.f, 0.f, 0.f}, acc1 = acc0, acc2 = acc0, acc3 = acc0;
    const int ar = w * 16 + m;       // A row
#pragma unroll
    for (int kk = 0; kk < 4; ++kk) {
        const int g = kk * 4 + kg;   // granule index of this fragment's 8 k
        const bf16x8 afr = ((const bf16x8*)sA)[ar * 16 + (g ^ (ar & 15))];
        {
            const int br = m;
            const bf16x8 bfr = ((const bf16x8*)sB)[br * 16 + (g ^ (br & 15))];
            acc0 = __builtin_amdgcn_mfma_f32_16x16x32_bf16(afr, bfr, acc0, 0, 0, 0);
        }
        {
            const int br = 16 + m;
            const bf16x8 bfr = ((const bf16x8*)sB)[br * 16 + (g ^ (br & 15))];
            acc1 = __builtin_amdgcn_mfma_f32_16x16x32_bf16(afr, bfr, acc1, 0, 0, 0);
        }
        {
            const int br = 32 + m;
            const bf16x8 bfr = ((const bf16x8*)sB)[br * 16 + (g ^ (br & 15))];
            acc2 = __builtin_amdgcn_mfma_f32_16x16x32_bf16(afr, bfr, acc2, 0, 0, 0);
        }
        {
            const int br = 48 + m;
            const bf16x8 bfr = ((const bf16x8*)sB)[br * 16 + (g ^ (br & 15))];
            acc3 = __builtin_amdgcn_mfma_f32_16x16x32_bf16(afr, bfr, acc3, 0, 0, 0);
        }
    }
    const int col = lane & 15;
    const int rb  = (lane >> 4) * 4;
    f32x4 av[4] = {acc0, acc1, acc2, acc3};
#pragma unroll
    for (int ni = 0; ni < 4; ++ni) {
        const int n = ni * 16 + col;
        const float bias = bl[n];
#pragma unroll
        for (int r = 0; r < 4; ++r) {
            const int node = base + w * 16 + rb + r;
            if (node < n1) {
                float v = av[ni][r] + bias;
                if (RELU) v = fmaxf(v, 0.f);
                if (out_f) out_f[(size_t)node * DIM + n] = v;
                if (out_b) out_b[(size_t)node * DIM + n] = pack_bf1(v);
            }
        }
    }
}

// ---------------------------------------------------------------------------
extern "C" void kernel_launch(void* const* d_in, const int* in_sizes, int n_in,
                              void* d_out, int out_size, void* d_ws, size_t ws_size,
                              hipStream_t stream) {
    const float* x_user  = (const float*)d_in[0];
    const float* x_movie = (const float*)d_in[1];
    const void*  e_src   = d_in[2];
    const void*  e_dst   = d_in[3];
    const float* W1_um_l = (const float*)d_in[4];
    const float* W1_um_r = (const float*)d_in[5];
    const float* W1_mu_l = (const float*)d_in[6];
    const float* W1_mu_r = (const float*)d_in[7];
    const float* W2_um_l = (const float*)d_in[8];
    const float* W2_um_r = (const float*)d_in[9];
    const float* W2_mu_l = (const float*)d_in[10];
    const float* W2_mu_r = (const float*)d_in[11];
    const float* b1_um = (const float*)d_in[12];
    const float* b1_mu = (const float*)d_in[13];
    const float* b2_um = (const float*)d_in[14];
    const float* b2_mu = (const float*)d_in[15];
    const int nE = in_sizes[2];
    const int cpb = (nE + G_SC - 1) / G_SC;

    auto al = [](size_t b) { return (b + 255) & ~(size_t)255; };
    const size_t fixed_b = al(4) + al(((size_t)NU + 1) * 4) + al(((size_t)NM + 1) * 4)
                         + 2 * al((size_t)MBK2 * G_SC * 4) + 2 * al((MBK2 + 1) * 4)
                         + 2 * al((size_t)nE * 4) + al(4 * 8192 * 2);
    const size_t a1_b = al((size_t)NU * DIM * 2);
    const size_t a2_b = al((size_t)NM * DIM * 2);
    const size_t pair_b = (size_t)2 * nE * 4;
    int CHKr = 50000;
    {
        const int cand[3] = {200000, 100000, 50000};
        for (int k = 0; k < 3; ++k) {
            size_t bphase = (size_t)cand[k] * DIM * 2 + (size_t)NM * DIM * 2 + 1024;
            size_t need = fixed_b + a1_b + a2_b +
                          al(bphase > pair_b ? bphase : pair_b) + 4096;
            if (need <= ws_size) { CHKr = cand[k]; break; }
        }
    }

    char* ws = (char*)d_ws;
    size_t off = 0;
    auto carve = [&](size_t bytes) {
        void* p = ws + off;
        off += al(bytes);
        return p;
    };
    int*      flag     = (int*)carve(4);
    int*      rp_u     = (int*)carve(((size_t)NU + 1) * 4);
    int*      rp_m     = (int*)carve(((size_t)NM + 1) * 4);
    int*      hist_m   = (int*)carve((size_t)MBK2 * G_SC * 4);
    int*      hist_u   = (int*)carve((size_t)MBK2 * G_SC * 4);
    int*      bounds_m = (int*)carve((MBK2 + 1) * 4);
    int*      bounds_u = (int*)carve((MBK2 + 1) * 4);
    int*      adj_u    = (int*)carve((size_t)nE * 4);
    int*      adj_m    = (int*)carve((size_t)nE * 4);
    ushort_t* wt_all   = (ushort_t*)carve(4 * 8192 * 2);    // 4 x [64][128] bf16
    ushort_t* A1 = (ushort_t*)carve((size_t)NU * DIM * 2);  // xu_bf then u1_bf
    ushort_t* A2 = (ushort_t*)carve((size_t)NM * DIM * 2);  // m1_bf
    size_t bphase = (size_t)CHKr * DIM * 2 + (size_t)NM * DIM * 2 + 1024;
    char*     B      = (char*)carve(bphase > pair_b ? bphase : pair_b);
    unsigned* pr_m   = (unsigned*)B;                        // phase A
    unsigned* pr_u   = (unsigned*)(B + (size_t)nE * 4);     // phase A
    ushort_t* agg_bf = (ushort_t*)B;                        // phase B
    ushort_t* xm_bf  = (ushort_t*)(B + al((size_t)CHKr * DIM * 2)); // phase B
    ushort_t* xu_bf  = A1;
    ushort_t* u1_bf  = A1;
    ushort_t* m1_bf  = A2;
    ushort_t* wt1m = wt_all;            // layer1 movie (W1_um)
    ushort_t* wt1u = wt_all + 8192;     // layer1 user  (W1_mu)
    ushort_t* wt2m = wt_all + 16384;    // layer2 movie (W2_um)
    ushort_t* wt2u = wt_all + 24576;    // layer2 user  (W2_mu)

    float* u2 = (float*)d_out;                    // [NU,64]
    float* m2 = (float*)d_out + (size_t)NU * DIM; // [NM,64]

    // ---- build CSR (both directions): radix binning, zero global atomics ----
    detect_idx_kernel<<<1, 256, 0, stream>>>((const unsigned int*)e_src, flag);
    count_kernel<<<G_SC, 256, 0, stream>>>(e_src, e_dst, flag,
                                           hist_m, hist_u, nE, cpb);
    hist_scan_kernel<<<2, 1024, 0, stream>>>(hist_m, hist_u,
                                             bounds_m, bounds_u, nE);
    pair_scatter_kernel<<<G_SC, 256, 0, stream>>>(e_src, e_dst, flag,
                                                  hist_m, hist_u, pr_m, pr_u,
                                                  nE, cpb);
    build_csr_kernel<<<2 * MBK2, 1024, 0, stream>>>(pr_m, pr_u,
                                                    bounds_m, bounds_u,
                                                    rp_m, rp_u, adj_m, adj_u, nE);
    // pr_m/pr_u dead from here; B switches to agg_bf/xm_bf.

    // ---- bf16 sources + transposed bf16 weights (one dispatch) ----
    conv_prep_kernel<<<2048, 256, 0, stream>>>((const float4*)x_user,
                                               (const float4*)x_movie,
                                               (uint2*)xu_bf, (uint2*)xm_bf,
                                               W1_um_l, W1_um_r, W1_mu_l, W1_mu_r,
                                               W2_um_l, W2_um_r, W2_mu_l, W2_mu_r,
                                               wt_all);

    auto run_dir = [&](const ushort_t* src_bf, const int* rp, const int* adj,
                       const ushort_t* xdst_bf, const ushort_t* wt,
                       const float* bl, float* outf, ushort_t* outb,
                       int n_tot, int relu) {
        for (int n0 = 0; n0 < n_tot; n0 += CHKr) {
            const int n1 = min(n_tot, n0 + CHKr);
            const int gb = (n1 - n0 + 31) / 32;     // 8 nodes/wave, 4 waves/blk
            const int tb = (n1 - n0 + 63) / 64;
            gather_mean_bf16_kernel<<<gb, 256, 0, stream>>>(src_bf, rp, adj,
                                                            agg_bf, n0, n1);
            if (relu)
                transform_mfma_kernel<1><<<tb, 256, 0, stream>>>(agg_bf, xdst_bf,
                    wt, bl, outf, outb, n0, n1);
            else
                transform_mfma_kernel<0><<<tb, 256, 0, stream>>>(agg_bf, xdst_bf,
                    wt, bl, outf, outb, n0, n1);
        }
    };

    // ---- layer 1 (bf16 intermediates only) ----
    run_dir(xu_bf, rp_m, adj_m, xm_bf, wt1m, b1_um, nullptr, m1_bf, NM, 1);
    run_dir(xm_bf, rp_u, adj_u, xu_bf, wt1u, b1_mu, nullptr, u1_bf, NU, 1);
    // ---- layer 2 (fp32 outputs straight to d_out) ----
    run_dir(u1_bf, rp_m, adj_m, m1_bf, wt2m, b2_um, m2, nullptr, NM, 0);
    run_dir(m1_bf, rp_u, adj_u, u1_bf, wt2u, b2_mu, u2, nullptr, NU, 0);
}

// Round 17
// 338.968 us; speedup vs baseline: 1.0846x; 1.0285x over previous
//
#include <hip/hip_runtime.h>
#include <stdint.h>

#define NU 200000
#define NM 100000
#define DIM 64
#define MBK2 64          // buckets per direction
#define SP_M 1563        // movie node span per bucket (ceil(NM/64))
#define SP_U 3125        // user  node span per bucket (NU/64)
#define G_SC 1024        // blocks for count/pair_scatter (fixed chunk assignment)

typedef unsigned short ushort_t;
typedef __attribute__((ext_vector_type(8))) short bf16x8;
typedef __attribute__((ext_vector_type(4))) float f32x4;

// ---------------------------------------------------------------------------
// bf16 helpers (RNE)
__device__ __forceinline__ unsigned pack_bf2(float lo, float hi) {
    unsigned ul = __float_as_uint(lo); ul += 0x7fffu + ((ul >> 16) & 1u);
    unsigned uh = __float_as_uint(hi); uh += 0x7fffu + ((uh >> 16) & 1u);
    return (ul >> 16) | (uh & 0xffff0000u);
}
__device__ __forceinline__ ushort_t pack_bf1(float v) {
    unsigned u = __float_as_uint(v); u += 0x7fffu + ((u >> 16) & 1u);
    return (ushort_t)(u >> 16);
}

// v_dot2_f32_bf16: acc += pair.lo*sel.lo + pair.hi*sel.hi (1 VALU op)
__device__ __forceinline__ void dot2_acc(float& acc, unsigned pair, unsigned sel) {
    asm("v_dot2_f32_bf16 %0, %1, %2, %0" : "+v"(acc) : "v"(pair), "v"(sel));
}
__device__ __forceinline__ void acc8(float* a, const uint4& v,
                                     unsigned SEL_LO, unsigned SEL_HI) {
    dot2_acc(a[0], v.x, SEL_LO); dot2_acc(a[1], v.x, SEL_HI);
    dot2_acc(a[2], v.y, SEL_LO); dot2_acc(a[3], v.y, SEL_HI);
    dot2_acc(a[4], v.z, SEL_LO); dot2_acc(a[5], v.z, SEL_HI);
    dot2_acc(a[6], v.w, SEL_LO); dot2_acc(a[7], v.w, SEL_HI);
}

// ---------------------------------------------------------------------------
// Detect whether edge index arrays are int64 or int32.
__global__ void detect_idx_kernel(const unsigned int* __restrict__ words,
                                  int* __restrict__ flag) {
    __shared__ int nz;
    if (threadIdx.x == 0) nz = 0;
    __syncthreads();
    for (int i = threadIdx.x; i < 2048; i += blockDim.x)
        if (words[2 * i + 1] != 0u) nz = 1;
    __syncthreads();
    if (threadIdx.x == 0) *flag = (nz == 0) ? 1 : 0;   // 1 => int64
}

__device__ __forceinline__ int load_idx(const void* __restrict__ p, int e, int is64) {
    if (is64) return (int)((const long long*)p)[e];
    return ((const int*)p)[e];
}

// ---------------------------------------------------------------------------
// Fused prep: fp32->bf16 (RNE) for BOTH feature tables + transposed bf16
// weight tables (4 x [64 n][128 k], k<64 = Wl[k][n], k>=64 = Wr[k-64][n]).
__global__ void conv_prep_kernel(const float4* __restrict__ xu,
                                 const float4* __restrict__ xm,
                                 uint2* __restrict__ xu_bf,
                                 uint2* __restrict__ xm_bf,
                                 const float* __restrict__ W1ml, const float* __restrict__ W1mr,
                                 const float* __restrict__ W1ul, const float* __restrict__ W1ur,
                                 const float* __restrict__ W2ml, const float* __restrict__ W2mr,
                                 const float* __restrict__ W2ul, const float* __restrict__ W2ur,
                                 ushort_t* __restrict__ wt) {
    const int nu4 = NU * 16, nm4 = NM * 16;
    const int stride = gridDim.x * blockDim.x;
    const int gid = blockIdx.x * blockDim.x + threadIdx.x;
    for (int i = gid; i < nu4 + nm4; i += stride) {
        if (i < nu4) {
            const float4 v = xu[i];
            xu_bf[i] = make_uint2(pack_bf2(v.x, v.y), pack_bf2(v.z, v.w));
        } else {
            const float4 v = xm[i - nu4];
            xm_bf[i - nu4] = make_uint2(pack_bf2(v.x, v.y), pack_bf2(v.z, v.w));
        }
    }
    if (gid < 4 * 8192) {
        const int tbl = gid >> 13, r = gid & 8191;
        const int n = r >> 7, k = r & 127;
        const float* Wl; const float* Wr;
        switch (tbl) {
            case 0:  Wl = W1ml; Wr = W1mr; break;
            case 1:  Wl = W1ul; Wr = W1ur; break;
            case 2:  Wl = W2ml; Wr = W2mr; break;
            default: Wl = W2ul; Wr = W2ur; break;
        }
        const float v = (k < 64) ? Wl[k * 64 + n] : Wr[(k - 64) * 64 + n];
        wt[gid] = pack_bf1(v);
    }
}

// ---------------------------------------------------------------------------
// Per-block 64-bucket histograms, both directions (bucket-major layout
// hist[b*G_SC + blk]); FIXED per-block edge chunks.
__global__ void count_kernel(const void* __restrict__ es, const void* __restrict__ ed,
                             const int* __restrict__ flag,
                             int* __restrict__ hist_m, int* __restrict__ hist_u,
                             int nE, int cpb) {
    __shared__ int h[2 * MBK2];
    if (threadIdx.x < 2 * MBK2) h[threadIdx.x] = 0;
    __syncthreads();
    const int is64 = *flag;
    const int e0 = blockIdx.x * cpb;
    const int e1 = min(nE, e0 + cpb);
    for (int e = e0 + threadIdx.x; e < e1; e += blockDim.x) {
        int s = load_idx(es, e, is64);
        int d = load_idx(ed, e, is64);
        atomicAdd(&h[(unsigned)d / SP_M], 1);
        atomicAdd(&h[MBK2 + (unsigned)s / SP_U], 1);
    }
    __syncthreads();
    if (threadIdx.x < MBK2)
        hist_m[threadIdx.x * G_SC + blockIdx.x] = h[threadIdx.x];
    else if (threadIdx.x < 2 * MBK2)
        hist_u[(threadIdx.x - MBK2) * G_SC + blockIdx.x] = h[threadIdx.x];
}

// ---------------------------------------------------------------------------
// Exclusive scan of per-block bucket histogram (64*G_SC, bucket-major) in
// place; emits bounds[0..64]. 2 blocks (movie, user).
__global__ __launch_bounds__(1024) void
hist_scan_kernel(int* __restrict__ hist_m, int* __restrict__ hist_u,
                 int* __restrict__ bounds_m, int* __restrict__ bounds_u, int nE) {
    int* hist   = (blockIdx.x == 0) ? hist_m : hist_u;
    int* bounds = (blockIdx.x == 0) ? bounds_m : bounds_u;
    const int t = threadIdx.x;          // 1024 threads x 64 = 64*G_SC
    const int base = t * 64;
    int v[64];
    int tot = 0;
#pragma unroll
    for (int k = 0; k < 64; ++k) { v[k] = hist[base + k]; tot += v[k]; }
    __shared__ int sc[1024];
    sc[t] = tot;
    __syncthreads();
    for (int off = 1; off < 1024; off <<= 1) {
        int x = (t >= off) ? sc[t - off] : 0;
        __syncthreads();
        sc[t] += x;
        __syncthreads();
    }
    int excl = sc[t] - tot;
#pragma unroll
    for (int k = 0; k < 64; ++k) { int tmp = v[k]; hist[base + k] = excl; excl += tmp; }
    __syncthreads();
    if (t < MBK2) bounds[t] = hist[t * G_SC];
    else if (t == MBK2) bounds[MBK2] = nE;
}

// ---------------------------------------------------------------------------
// Level-1 scatter, deterministic (LDS cursors, exclusive per-bucket chunks).
__global__ void pair_scatter_kernel(const void* __restrict__ es,
                                    const void* __restrict__ ed,
                                    const int* __restrict__ flag,
                                    const int* __restrict__ hist_m,
                                    const int* __restrict__ hist_u,
                                    unsigned* __restrict__ pr_m,
                                    unsigned* __restrict__ pr_u,
                                    int nE, int cpb) {
    __shared__ int cur[2 * MBK2];
    if (threadIdx.x < MBK2)
        cur[threadIdx.x] = hist_m[threadIdx.x * G_SC + blockIdx.x];
    else if (threadIdx.x < 2 * MBK2)
        cur[threadIdx.x] = hist_u[(threadIdx.x - MBK2) * G_SC + blockIdx.x];
    __syncthreads();
    const int is64 = *flag;
    const int e0 = blockIdx.x * cpb;
    const int e1 = min(nE, e0 + cpb);
    for (int e = e0 + threadIdx.x; e < e1; e += blockDim.x) {
        const int s = load_idx(es, e, is64);
        const int d = load_idx(ed, e, is64);
        const int b0 = (unsigned)d / SP_M;
        const int b1 = (unsigned)s / SP_U;
        const int p0 = atomicAdd(&cur[b0], 1);
        pr_m[p0] = ((unsigned)(d - b0 * SP_M) << 18) | (unsigned)s;
        const int p1 = atomicAdd(&cur[MBK2 + b1], 1);
        pr_u[p1] = ((unsigned)(s - b1 * SP_U) << 17) | (unsigned)d;
    }
}

// ---------------------------------------------------------------------------
// Merged CSR build: ONE block per bucket (LDS degree hist -> LDS scan ->
// rowptr write -> adj fill into XCD-exclusive region). Both streaming loops
// are 4-deep unrolled with batched pr loads so each wave keeps 4 L2 loads in
// flight instead of serializing load->LDS-atomic->store per iteration.
__global__ __launch_bounds__(1024) void
build_csr_kernel(const unsigned* __restrict__ pr_m, const unsigned* __restrict__ pr_u,
                 const int* __restrict__ bounds_m, const int* __restrict__ bounds_u,
                 int* __restrict__ rp_m, int* __restrict__ rp_u,
                 int* __restrict__ adj_m, int* __restrict__ adj_u, int nE) {
    __shared__ int cur[SP_U];
    __shared__ int ps[1024];
    const int t = threadIdx.x;
    const int b = blockIdx.x;
    const bool mv = (b < MBK2);
    const int bb = mv ? b : b - MBK2;
    const int span  = mv ? SP_M : SP_U;
    const int shift = mv ? 18 : 17;
    const unsigned mask = (1u << shift) - 1u;
    const unsigned* pr = mv ? pr_m : pr_u;
    const int* bounds  = mv ? bounds_m : bounds_u;
    int* rp  = mv ? rp_m : rp_u;
    int* adj = mv ? adj_m : adj_u;
    const int n_tot = mv ? NM : NU;
    const int nb = bb * span;
    const int s0 = bounds[bb], s1 = bounds[bb + 1];

    for (int i = t; i < span; i += 1024) cur[i] = 0;
    __syncthreads();
    // histogram phase, 4-deep unrolled (batched loads)
    {
        int i = s0 + t;
        for (; i + 3 * 1024 < s1; i += 4 * 1024) {
            const unsigned w0 = pr[i];
            const unsigned w1 = pr[i + 1024];
            const unsigned w2 = pr[i + 2048];
            const unsigned w3 = pr[i + 3072];
            atomicAdd(&cur[w0 >> shift], 1);
            atomicAdd(&cur[w1 >> shift], 1);
            atomicAdd(&cur[w2 >> shift], 1);
            atomicAdd(&cur[w3 >> shift], 1);
        }
        for (; i < s1; i += 1024)
            atomicAdd(&cur[pr[i] >> shift], 1);
    }
    __syncthreads();
    int v[4];
    int loc = 0;
#pragma unroll
    for (int k = 0; k < 4; ++k) {
        const int i = t * 4 + k;
        v[k] = (i < span) ? cur[i] : 0;
        loc += v[k];
    }
    ps[t] = loc;
    __syncthreads();
    for (int off = 1; off < 1024; off <<= 1) {
        int x = (t >= off) ? ps[t - off] : 0;
        __syncthreads();
        ps[t] += x;
        __syncthreads();
    }
    int run = s0 + ps[t] - loc;
#pragma unroll
    for (int k = 0; k < 4; ++k) {
        const int i = t * 4 + k;
        if (i < span) {
            if (nb + i < n_tot) rp[nb + i] = run;
            cur[i] = run;
            run += v[k];
        }
    }
    if (bb == MBK2 - 1 && t == 0) rp[n_tot] = nE;   // sentinel
    __syncthreads();
    // fill phase, 4-deep unrolled (batched loads, then atomics, then stores)
    {
        int i = s0 + t;
        for (; i + 3 * 1024 < s1; i += 4 * 1024) {
            const unsigned w0 = pr[i];
            const unsigned w1 = pr[i + 1024];
            const unsigned w2 = pr[i + 2048];
            const unsigned w3 = pr[i + 3072];
            const int p0 = atomicAdd(&cur[w0 >> shift], 1);
            const int p1 = atomicAdd(&cur[w1 >> shift], 1);
            const int p2 = atomicAdd(&cur[w2 >> shift], 1);
            const int p3 = atomicAdd(&cur[w3 >> shift], 1);
            adj[p0] = (int)(w0 & mask);
            adj[p1] = (int)(w1 & mask);
            adj[p2] = (int)(w2 & mask);
            adj[p3] = (int)(w3 & mask);
        }
        for (; i < s1; i += 1024) {
            const unsigned w = pr[i];
            const int slot = atomicAdd(&cur[w >> shift], 1);
            adj[slot] = (int)(w & mask);
        }
    }
}

// ---------------------------------------------------------------------------
// bf16 mean-aggregate gather, GROUP-PER-NODE layout: 8 nodes per wave, one
// node per 8-lane group (col = lane&7 owns dims 8c..8c+7). Each group walks
// its adjacency with a 4-deep unroll -> 32 distinct rows in flight per wave.
// No cross-lane reduction. Writes: 8 consecutive rows = 1KB coalesced.
__global__ __launch_bounds__(256) void
gather_mean_bf16_kernel(const ushort_t* __restrict__ xsrc,
                        const int* __restrict__ rowptr,
                        const int* __restrict__ adj,
                        ushort_t* __restrict__ agg,
                        int n0, int n1) {
    const unsigned SEL_LO = 0x00003f80u;   // bf16 (1.0, 0)
    const unsigned SEL_HI = 0x3f800000u;   // bf16 (0, 1.0)
    const int lane = threadIdx.x & 63;
    const int grp  = lane >> 3;            // node group 0..7
    const int col  = lane & 7;             // uint4 column (16B)
    const int wid  = (blockIdx.x * blockDim.x + threadIdx.x) >> 6;
    const int nw   = (gridDim.x * blockDim.x) >> 6;
    for (int ib = n0 + wid * 8; ib < n1; ib += nw * 8) {
        const int i = ib + grp;
        float a[8] = {0.f, 0.f, 0.f, 0.f, 0.f, 0.f, 0.f, 0.f};
        float b[8] = {0.f, 0.f, 0.f, 0.f, 0.f, 0.f, 0.f, 0.f};
        int r0 = 0, r1 = 0;
        if (i < n1) { r0 = rowptr[i]; r1 = rowptr[i + 1]; }
        int j = r0;
        for (; j + 3 < r1; j += 4) {
            const int s0 = adj[j];
            const int s1 = adj[j + 1];
            const int s2 = adj[j + 2];
            const int s3 = adj[j + 3];
            const uint4 v0 = ((const uint4*)(xsrc + (size_t)s0 * DIM))[col];
            const uint4 v1 = ((const uint4*)(xsrc + (size_t)s1 * DIM))[col];
            const uint4 v2 = ((const uint4*)(xsrc + (size_t)s2 * DIM))[col];
            const uint4 v3 = ((const uint4*)(xsrc + (size_t)s3 * DIM))[col];
            acc8(a, v0, SEL_LO, SEL_HI);
            acc8(b, v1, SEL_LO, SEL_HI);
            acc8(a, v2, SEL_LO, SEL_HI);
            acc8(b, v3, SEL_LO, SEL_HI);
        }
        for (; j < r1; ++j) {
            const int s0 = adj[j];
            const uint4 v0 = ((const uint4*)(xsrc + (size_t)s0 * DIM))[col];
            acc8(a, v0, SEL_LO, SEL_HI);
        }
#pragma unroll
        for (int k = 0; k < 8; ++k) a[k] += b[k];
        if (i < n1) {
            const float inv = 1.0f / fmaxf((float)(r1 - r0), 1.0f);
            uint4 o;
            o.x = pack_bf2(a[0] * inv, a[1] * inv);
            o.y = pack_bf2(a[2] * inv, a[3] * inv);
            o.z = pack_bf2(a[4] * inv, a[5] * inv);
            o.w = pack_bf2(a[6] * inv, a[7] * inv);
            ((uint4*)(agg + (size_t)(i - n0) * DIM))[col] = o;
        }
    }
}

// ---------------------------------------------------------------------------
// MFMA transform: C[64][64] = [agg|xdst] @ wt + b.
template <int RELU>
__global__ __launch_bounds__(256) void
transform_mfma_kernel(const ushort_t* __restrict__ agg,
                      const ushort_t* __restrict__ xdst_b,
                      const ushort_t* __restrict__ wt,
                      const float* __restrict__ bl,
                      float* __restrict__ out_f,
                      ushort_t* __restrict__ out_b,
                      int n0, int n1) {
    __shared__ ushort_t sA[64 * 128];   // 16KB, swizzled granules
    __shared__ ushort_t sB[64 * 128];   // 16KB, swizzled granules

    const int tid = threadIdx.x;
    const int base = n0 + blockIdx.x * 64;
    {
        const uint4* w4 = (const uint4*)wt;
#pragma unroll
        for (int i = 0; i < 4; ++i) {
            const int idx = i * 256 + tid;        // 0..1023
            const int row = idx >> 4;             // n
            const int g   = idx & 15;             // granule (8 bf16)
            ((uint4*)sB)[row * 16 + (g ^ (row & 15))] = w4[idx];
        }
    }
#pragma unroll
    for (int i = 0; i < 4; ++i) {
        const int idx = i * 256 + tid;
        const int ln   = idx >> 4;                // node local 0..63
        const int g    = idx & 15;                // granule: 0-7 agg, 8-15 xdst
        const int node = base + ln;
        uint4 v = make_uint4(0, 0, 0, 0);
        if (node < n1)
            v = (g < 8) ? ((const uint4*)(agg + (size_t)(node - n0) * DIM))[g]
                        : ((const uint4*)(xdst_b + (size_t)node * DIM))[g - 8];
        ((uint4*)sA)[ln * 16 + (g ^ (ln & 15))] = v;
    }
    __syncthreads();

    const int w    = tid >> 6;       // wave 0..3 -> node rows w*16..+15
    const int lane = tid & 63;
    const int m    = lane & 15;
    const int kg   = lane >> 4;      // k-group (8 bf16 each)
    f32x4 acc0 = {0.f, 0.f, 0.f, 0.f}, acc1 = acc0, acc2 = acc0, acc3 = acc0;
    const int ar = w * 16 + m;       // A row
#pragma unroll
    for (int kk = 0; kk < 4; ++kk) {
        const int g = kk * 4 + kg;   // granule index of this fragment's 8 k
        const bf16x8 afr = ((const bf16x8*)sA)[ar * 16 + (g ^ (ar & 15))];
        {
            const int br = m;
            const bf16x8 bfr = ((const bf16x8*)sB)[br * 16 + (g ^ (br & 15))];
            acc0 = __builtin_amdgcn_mfma_f32_16x16x32_bf16(afr, bfr, acc0, 0, 0, 0);
        }
        {
            const int br = 16 + m;
            const bf16x8 bfr = ((const bf16x8*)sB)[br * 16 + (g ^ (br & 15))];
            acc1 = __builtin_amdgcn_mfma_f32_16x16x32_bf16(afr, bfr, acc1, 0, 0, 0);
        }
        {
            const int br = 32 + m;
            const bf16x8 bfr = ((const bf16x8*)sB)[br * 16 + (g ^ (br & 15))];
            acc2 = __builtin_amdgcn_mfma_f32_16x16x32_bf16(afr, bfr, acc2, 0, 0, 0);
        }
        {
            const int br = 48 + m;
            const bf16x8 bfr = ((const bf16x8*)sB)[br * 16 + (g ^ (br & 15))];
            acc3 = __builtin_amdgcn_mfma_f32_16x16x32_bf16(afr, bfr, acc3, 0, 0, 0);
        }
    }
    const int col = lane & 15;
    const int rb  = (lane >> 4) * 4;
    f32x4 av[4] = {acc0, acc1, acc2, acc3};
#pragma unroll
    for (int ni = 0; ni < 4; ++ni) {
        const int n = ni * 16 + col;
        const float bias = bl[n];
#pragma unroll
        for (int r = 0; r < 4; ++r) {
            const int node = base + w * 16 + rb + r;
            if (node < n1) {
                float v = av[ni][r] + bias;
                if (RELU) v = fmaxf(v, 0.f);
                if (out_f) out_f[(size_t)node * DIM + n] = v;
                if (out_b) out_b[(size_t)node * DIM + n] = pack_bf1(v);
            }
        }
    }
}

// ---------------------------------------------------------------------------
extern "C" void kernel_launch(void* const* d_in, const int* in_sizes, int n_in,
                              void* d_out, int out_size, void* d_ws, size_t ws_size,
                              hipStream_t stream) {
    const float* x_user  = (const float*)d_in[0];
    const float* x_movie = (const float*)d_in[1];
    const void*  e_src   = d_in[2];
    const void*  e_dst   = d_in[3];
    const float* W1_um_l = (const float*)d_in[4];
    const float* W1_um_r = (const float*)d_in[5];
    const float* W1_mu_l = (const float*)d_in[6];
    const float* W1_mu_r = (const float*)d_in[7];
    const float* W2_um_l = (const float*)d_in[8];
    const float* W2_um_r = (const float*)d_in[9];
    const float* W2_mu_l = (const float*)d_in[10];
    const float* W2_mu_r = (const float*)d_in[11];
    const float* b1_um = (const float*)d_in[12];
    const float* b1_mu = (const float*)d_in[13];
    const float* b2_um = (const float*)d_in[14];
    const float* b2_mu = (const float*)d_in[15];
    const int nE = in_sizes[2];
    const int cpb = (nE + G_SC - 1) / G_SC;

    auto al = [](size_t b) { return (b + 255) & ~(size_t)255; };
    const size_t fixed_b = al(4) + al(((size_t)NU + 1) * 4) + al(((size_t)NM + 1) * 4)
                         + 2 * al((size_t)MBK2 * G_SC * 4) + 2 * al((MBK2 + 1) * 4)
                         + 2 * al((size_t)nE * 4) + al(4 * 8192 * 2);
    const size_t a1_b = al((size_t)NU * DIM * 2);
    const size_t a2_b = al((size_t)NM * DIM * 2);
    const size_t pair_b = (size_t)2 * nE * 4;
    int CHKr = 50000;
    {
        const int cand[3] = {200000, 100000, 50000};
        for (int k = 0; k < 3; ++k) {
            size_t bphase = (size_t)cand[k] * DIM * 2 + (size_t)NM * DIM * 2 + 1024;
            size_t need = fixed_b + a1_b + a2_b +
                          al(bphase > pair_b ? bphase : pair_b) + 4096;
            if (need <= ws_size) { CHKr = cand[k]; break; }
        }
    }

    char* ws = (char*)d_ws;
    size_t off = 0;
    auto carve = [&](size_t bytes) {
        void* p = ws + off;
        off += al(bytes);
        return p;
    };
    int*      flag     = (int*)carve(4);
    int*      rp_u     = (int*)carve(((size_t)NU + 1) * 4);
    int*      rp_m     = (int*)carve(((size_t)NM + 1) * 4);
    int*      hist_m   = (int*)carve((size_t)MBK2 * G_SC * 4);
    int*      hist_u   = (int*)carve((size_t)MBK2 * G_SC * 4);
    int*      bounds_m = (int*)carve((MBK2 + 1) * 4);
    int*      bounds_u = (int*)carve((MBK2 + 1) * 4);
    int*      adj_u    = (int*)carve((size_t)nE * 4);
    int*      adj_m    = (int*)carve((size_t)nE * 4);
    ushort_t* wt_all   = (ushort_t*)carve(4 * 8192 * 2);    // 4 x [64][128] bf16
    ushort_t* A1 = (ushort_t*)carve((size_t)NU * DIM * 2);  // xu_bf then u1_bf
    ushort_t* A2 = (ushort_t*)carve((size_t)NM * DIM * 2);  // m1_bf
    size_t bphase = (size_t)CHKr * DIM * 2 + (size_t)NM * DIM * 2 + 1024;
    char*     B      = (char*)carve(bphase > pair_b ? bphase : pair_b);
    unsigned* pr_m   = (unsigned*)B;                        // phase A
    unsigned* pr_u   = (unsigned*)(B + (size_t)nE * 4);     // phase A
    ushort_t* agg_bf = (ushort_t*)B;                        // phase B
    ushort_t* xm_bf  = (ushort_t*)(B + al((size_t)CHKr * DIM * 2)); // phase B
    ushort_t* xu_bf  = A1;
    ushort_t* u1_bf  = A1;
    ushort_t* m1_bf  = A2;
    ushort_t* wt1m = wt_all;            // layer1 movie (W1_um)
    ushort_t* wt1u = wt_all + 8192;     // layer1 user  (W1_mu)
    ushort_t* wt2m = wt_all + 16384;    // layer2 movie (W2_um)
    ushort_t* wt2u = wt_all + 24576;    // layer2 user  (W2_mu)

    float* u2 = (float*)d_out;                    // [NU,64]
    float* m2 = (float*)d_out + (size_t)NU * DIM; // [NM,64]

    // ---- build CSR (both directions): radix binning, zero global atomics ----
    detect_idx_kernel<<<1, 256, 0, stream>>>((const unsigned int*)e_src, flag);
    count_kernel<<<G_SC, 256, 0, stream>>>(e_src, e_dst, flag,
                                           hist_m, hist_u, nE, cpb);
    hist_scan_kernel<<<2, 1024, 0, stream>>>(hist_m, hist_u,
                                             bounds_m, bounds_u, nE);
    pair_scatter_kernel<<<G_SC, 256, 0, stream>>>(e_src, e_dst, flag,
                                                  hist_m, hist_u, pr_m, pr_u,
                                                  nE, cpb);
    build_csr_kernel<<<2 * MBK2, 1024, 0, stream>>>(pr_m, pr_u,
                                                    bounds_m, bounds_u,
                                                    rp_m, rp_u, adj_m, adj_u, nE);
    // pr_m/pr_u dead from here; B switches to agg_bf/xm_bf.

    // ---- bf16 sources + transposed bf16 weights (one dispatch) ----
    conv_prep_kernel<<<2048, 256, 0, stream>>>((const float4*)x_user,
                                               (const float4*)x_movie,
                                               (uint2*)xu_bf, (uint2*)xm_bf,
                                               W1_um_l, W1_um_r, W1_mu_l, W1_mu_r,
                                               W2_um_l, W2_um_r, W2_mu_l, W2_mu_r,
                                               wt_all);

    auto run_dir = [&](const ushort_t* src_bf, const int* rp, const int* adj,
                       const ushort_t* xdst_bf, const ushort_t* wt,
                       const float* bl, float* outf, ushort_t* outb,
                       int n_tot, int relu) {
        for (int n0 = 0; n0 < n_tot; n0 += CHKr) {
            const int n1 = min(n_tot, n0 + CHKr);
            const int gb = (n1 - n0 + 31) / 32;     // 8 nodes/wave, 4 waves/blk
            const int tb = (n1 - n0 + 63) / 64;
            gather_mean_bf16_kernel<<<gb, 256, 0, stream>>>(src_bf, rp, adj,
                                                            agg_bf, n0, n1);
            if (relu)
                transform_mfma_kernel<1><<<tb, 256, 0, stream>>>(agg_bf, xdst_bf,
                    wt, bl, outf, outb, n0, n1);
            else
                transform_mfma_kernel<0><<<tb, 256, 0, stream>>>(agg_bf, xdst_bf,
                    wt, bl, outf, outb, n0, n1);
        }
    };

    // ---- layer 1 (bf16 intermediates only) ----
    run_dir(xu_bf, rp_m, adj_m, xm_bf, wt1m, b1_um, nullptr, m1_bf, NM, 1);
    run_dir(xm_bf, rp_u, adj_u, xu_bf, wt1u, b1_mu, nullptr, u1_bf, NU, 1);
    // ---- layer 2 (fp32 outputs straight to d_out) ----
    run_dir(u1_bf, rp_m, adj_m, m1_bf, wt2m, b2_um, m2, nullptr, NM, 0);
    run_dir(m1_bf, rp_u, adj_u, u1_bf, wt2u, b2_mu, u2, nullptr, NU, 0);
}